// Round 2
// baseline (868.847 us; speedup 1.0000x reference)
//
#include <hip/hip_runtime.h>

#define B_ 256
#define T_ 2048
#define H_ 64

typedef float f32x2 __attribute__((ext_vector_type(2)));
typedef float f32x4 __attribute__((ext_vector_type(4)));

__device__ __forceinline__ float fast_sigmoid(float v) {
    // 1/(1+e^-v) = rcp(1 + exp2(-v*log2e))
    float e = __builtin_amdgcn_exp2f(-1.4426950408889634f * v);
    return __builtin_amdgcn_rcpf(1.0f + e);
}

__device__ __forceinline__ float fast_tanh(float v) {
    // tanh(v) = 1 - 2/(1 + e^(2v))
    float e = __builtin_amdgcn_exp2f(2.8853900817779268f * v);
    return fmaf(-2.0f, __builtin_amdgcn_rcpf(1.0f + e), 1.0f);
}

__device__ __forceinline__ float readlane_f(float v, int idx) {
    return __builtin_bit_cast(float,
        __builtin_amdgcn_readlane(__builtin_bit_cast(int, v), idx));
}

// One wave (64 lanes) per batch row. Lane j owns hidden channel j and computes
// ALL THREE gate rows (r, z, n) for it -> no inter-wave gate exchange, no
// __syncthreads, zero barriers. h lives in a 64-float LDS buffer; per step:
// 1 ds_write_b32 (own channel) + 16 broadcast ds_read_b128 (uniform address,
// conflict-free) feeding 96 v_pk_fma_f32. x is loaded once per 64 steps
// (coalesced, prefetched a block ahead) and distributed via v_readlane.
__global__ __launch_bounds__(64, 1)
void gru_kernel(const float* __restrict__ x,
                const float* __restrict__ W_ih,
                const float* __restrict__ W_hh,
                const float* __restrict__ b_ih,
                const float* __restrict__ b_hh,
                float* __restrict__ out)
{
    __shared__ float shh[H_];

    const int lane = threadIdx.x;
    const int b    = blockIdx.x;

    // ---- preload W_hh rows {lane, 64+lane, 128+lane} into 192 VGPRs ----
    f32x2 wr[32], wz[32], wn[32];
    {
        const f32x4* pr = (const f32x4*)(W_hh + (size_t)lane * H_);
        const f32x4* pz = (const f32x4*)(W_hh + (size_t)(64 + lane) * H_);
        const f32x4* pn = (const f32x4*)(W_hh + (size_t)(128 + lane) * H_);
        #pragma unroll
        for (int q = 0; q < 16; ++q) {
            f32x4 vr = pr[q], vz = pz[q], vn = pn[q];
            wr[2*q] = f32x2{vr.x, vr.y}; wr[2*q+1] = f32x2{vr.z, vr.w};
            wz[2*q] = f32x2{vz.x, vz.y}; wz[2*q+1] = f32x2{vz.z, vz.w};
            wn[2*q] = f32x2{vn.x, vn.y}; wn[2*q+1] = f32x2{vn.z, vn.w};
        }
    }

    const float wihr = W_ih[lane];
    const float wihz = W_ih[64 + lane];
    const float wihn = W_ih[128 + lane];
    const float br   = b_ih[lane]       + b_hh[lane];
    const float bz   = b_ih[64 + lane]  + b_hh[64 + lane];
    const float bhn  = b_hh[128 + lane];
    const float bin  = b_ih[128 + lane];

    const float* __restrict__ xrow = x + (size_t)b * T_;
    float* __restrict__ orow = out + (size_t)b * T_;

    shh[lane] = 0.0f;          // h0 = 0; single wave: ds ops in order

    float h_own = 0.0f;        // lane j's own channel
    float oval  = 0.0f;        // staged output for coalesced store
    float xa = xrow[lane];     // current 64-block of x (lane i: x[t0+i])
    float xb = 0.0f;           // prefetched next block

    for (int t = 0; t < T_; ++t) {
        const int tt = t & 63;
        if (tt == 0) {                       // wave-uniform branch
            if (t != 0) {
                orow[t - 64 + lane] = oval;  // coalesced 256B store / 64 steps
                xa = xb;
            }
            if (t + 64 < T_) xb = xrow[t + 64 + lane];  // prefetch next block
        }
        const float xt = readlane_f(xa, tt); // uniform x[t]

        // ---- 3 gate dots over h (from LDS, broadcast reads) ----
        f32x2 ar0 = {0.f,0.f}, ar1 = {0.f,0.f};
        f32x2 az0 = {0.f,0.f}, az1 = {0.f,0.f};
        f32x2 an0 = {0.f,0.f}, an1 = {0.f,0.f};
        const f32x4* hp = (const f32x4*)shh;
        #pragma unroll
        for (int q = 0; q < 16; ++q) {
            f32x4 hv = hp[q];                // broadcast ds_read_b128
            f32x2 h01 = {hv.x, hv.y}, h23 = {hv.z, hv.w};
            ar0 += wr[2*q] * h01;  ar1 += wr[2*q+1] * h23;
            az0 += wz[2*q] * h01;  az1 += wz[2*q+1] * h23;
            an0 += wn[2*q] * h01;  an1 += wn[2*q+1] * h23;
        }
        f32x2 sr = ar0 + ar1, sz = az0 + az1, sn = an0 + an1;

        float r  = fast_sigmoid(sr.x + sr.y + fmaf(xt, wihr, br));
        float z  = fast_sigmoid(sz.x + sz.y + fmaf(xt, wihz, bz));
        float hn = sn.x + sn.y + bhn;
        float xn = fmaf(xt, wihn, bin);
        float n  = fast_tanh(fmaf(r, hn, xn));
        float h_new = n + z * (h_own - n);   // (1-z)*n + z*h
        h_own = h_new;

        shh[lane] = h_new;                   // publish for next step's dot

        // out[t] = h_new[63]; latch in lane (t&63), store once per block
        float h63 = readlane_f(h_new, 63);
        oval = (tt == lane) ? h63 : oval;
    }
    orow[T_ - 64 + lane] = oval;             // last block
}

extern "C" void kernel_launch(void* const* d_in, const int* in_sizes, int n_in,
                              void* d_out, int out_size, void* d_ws, size_t ws_size,
                              hipStream_t stream) {
    const float* x    = (const float*)d_in[0];
    const float* W_ih = (const float*)d_in[1];
    const float* W_hh = (const float*)d_in[2];
    const float* b_ih = (const float*)d_in[3];
    const float* b_hh = (const float*)d_in[4];
    float* out = (float*)d_out;

    dim3 grid(B_), block(64);
    gru_kernel<<<grid, block, 0, stream>>>(x, W_ih, W_hh, b_ih, b_hh, out);
}